// Round 7
// baseline (624.899 us; speedup 1.0000x reference)
//
#include <hip/hip_runtime.h>
#include <hip/hip_bf16.h>

#define HDIM 64
#define LSEQ 1024
#define NB 64
#define NV 32000
#define CC 32            // chunk length
#define NCH 32           // chunks per sequence
#define NT (NB * LSEQ)   // total tokens = kallT row stride

// ---------- DPP cross-lane sums (pure VALU) ----------
template<int CTRL>
__device__ __forceinline__ float dpp_red(float x) {
  int y = __builtin_amdgcn_update_dpp(0, __float_as_int(x), CTRL, 0xF, 0xF, true);
  return x + __int_as_float(y);
}
__device__ __forceinline__ float quad_sum(float x) {
  x = dpp_red<0xB1>(x);    // xor 1
  x = dpp_red<0x4E>(x);    // xor 2
  return x;
}
__device__ __forceinline__ float wave_sum(float x) {
  x = dpp_red<0xB1>(x);
  x = dpp_red<0x4E>(x);
  x = dpp_red<0x141>(x);   // row_half_mirror -> sum of 8
  x = dpp_red<0x140>(x);   // row_mirror      -> sum of 16
  float a = __int_as_float(__builtin_amdgcn_readlane(__float_as_int(x), 0));
  float b = __int_as_float(__builtin_amdgcn_readlane(__float_as_int(x), 16));
  float c = __int_as_float(__builtin_amdgcn_readlane(__float_as_int(x), 32));
  float d = __int_as_float(__builtin_amdgcn_readlane(__float_as_int(x), 48));
  return (a + b) + (c + d);
}

// ---------- Kernel 0: transpose W1 (64x128 -> 128x64) and kpW (64x64) ----------
__global__ __launch_bounds__(256) void transpose_w(const float* __restrict__ W1,
    const float* __restrict__ kpW, float* __restrict__ W1T, float* __restrict__ kpWT)
{
  const int tid = blockIdx.x * 256 + threadIdx.x;
  if (tid < 8192) { const int c = tid >> 6, j = tid & 63; W1T[tid] = W1[j * 128 + c]; }
  else { const int e = tid - 8192; const int i = e >> 6, j = e & 63; kpWT[e] = kpW[j * 64 + i]; }
}

// ---------- Kernel 1: token transform, lane = token ----------
__global__ __launch_bounds__(256, 1) void tok4(
    const int* __restrict__ seq, const float* __restrict__ embed,
    const float* __restrict__ W1T, const float* __restrict__ b1,
    const float* __restrict__ W2, const float* __restrict__ b2,
    const float* __restrict__ gamma, const float* __restrict__ beta,
    const float* __restrict__ kpWT, float* __restrict__ kallT,
    float* __restrict__ thr2_all, float* __restrict__ inv_all)
{
  const int tok = blockIdx.x * 256 + threadIdx.x;
  const int row = seq[tok];
  float h[64], x[64];
  const float4* ep = (const float4*)(embed + (size_t)row * HDIM);
  #pragma unroll
  for (int q = 0; q < 16; ++q) {
    const float4 v = ep[q];
    h[4*q] = v.x; h[4*q+1] = v.y; h[4*q+2] = v.z; h[4*q+3] = v.w;
  }
  #pragma unroll
  for (int j = 0; j < 64; ++j) x[j] = h[j] + b2[j];

  for (int c = 0; c < 128; ++c) {
    const float* w1r = W1T + c * 64;                   // uniform row -> s_load
    float a0 = 0.f, a1 = 0.f, a2 = 0.f, a3 = 0.f;
    #pragma unroll
    for (int j = 0; j < 64; j += 4) {
      a0 = fmaf(h[j],   w1r[j],   a0);
      a1 = fmaf(h[j+1], w1r[j+1], a1);
      a2 = fmaf(h[j+2], w1r[j+2], a2);
      a3 = fmaf(h[j+3], w1r[j+3], a3);
    }
    const float y = fmaxf(b1[c] + ((a0 + a1) + (a2 + a3)), 0.f);
    const float* w2r = W2 + c * 64;
    #pragma unroll
    for (int j = 0; j < 64; ++j) x[j] = fmaf(y, w2r[j], x[j]);
  }

  float s0=0.f,s1=0.f,s2=0.f,s3=0.f,q0=0.f,q1=0.f,q2=0.f,q3=0.f;
  #pragma unroll
  for (int j = 0; j < 64; j += 4) {
    s0 += x[j]; s1 += x[j+1]; s2 += x[j+2]; s3 += x[j+3];
    q0 = fmaf(x[j],   x[j],   q0); q1 = fmaf(x[j+1], x[j+1], q1);
    q2 = fmaf(x[j+2], x[j+2], q2); q3 = fmaf(x[j+3], x[j+3], q3);
  }
  const float mu  = ((s0+s1)+(s2+s3)) * (1.f/64.f);
  const float var = ((q0+q1)+(q2+q3)) * (1.f/64.f) - mu * mu;
  const float rs  = rsqrtf(var + 1e-5f);
  #pragma unroll
  for (int j = 0; j < 64; ++j) h[j] = (x[j] - mu) * rs * gamma[j] + beta[j];

  float nk2 = 0.f;
  for (int i = 0; i < 64; ++i) {
    const float* kr = kpWT + i * 64;                   // uniform row -> s_load
    float c0=0.f,c1=0.f,c2=0.f,c3=0.f;
    #pragma unroll
    for (int j = 0; j < 64; j += 4) {
      c0 = fmaf(h[j],   kr[j],   c0);
      c1 = fmaf(h[j+1], kr[j+1], c1);
      c2 = fmaf(h[j+2], kr[j+2], c2);
      c3 = fmaf(h[j+3], kr[j+3], c3);
    }
    const float ki = (c0 + c1) + (c2 + c3);
    nk2 = fmaf(ki, ki, nk2);
    kallT[(size_t)i * NT + tok] = ki;
  }
  thr2_all[tok] = 0.16f * nk2;
  inv_all[tok]  = 1.f / fmaxf(sqrtf(nk2), 1e-12f);
}

// ---------- Kernel 2: Gram, 4 chunks per block via LDS slab ----------
// grid NB*8 blocks x 256 threads; block stages 64x128 token slab (32 KB),
// wave w computes the 32x32 normalized Gram of chunk 4*g+w.
__global__ __launch_bounds__(256, 1) void gram3(const float* __restrict__ kallT,
    const float* __restrict__ inv_all, float* __restrict__ Gg)
{
  __shared__ float kS4[64 * 128];     // [feature][token-in-slab]
  const int bi = blockIdx.x;          // b*8 + g4
  const int b = bi >> 3, g4 = bi & 7;
  const int tid = threadIdx.x;
  const size_t gb = (size_t)b * LSEQ + g4 * 128;

  // stage: 8192 floats = 2048 float4; thread e covers (row j = e>>5, f4 pos e&31)
  #pragma unroll
  for (int q = 0; q < 8; ++q) {
    const int e = q * 256 + tid;
    const int j = e >> 5, p = e & 31;
    ((float4*)kS4)[(j << 5) + p] =
        *(const float4*)(kallT + (size_t)j * NT + gb + p * 4);
  }
  __syncthreads();

  const int w = tid >> 6, l = tid & 63;
  const int tb = w * 32;              // chunk token base within slab
  const int t0 = (l & 7) * 4, s0 = (l >> 3) * 4;
  float g00=0,g01=0,g02=0,g03=0, g10=0,g11=0,g12=0,g13=0;
  float g20=0,g21=0,g22=0,g23=0, g30=0,g31=0,g32=0,g33=0;
  #pragma unroll 8
  for (int j = 0; j < 64; ++j) {
    const float* rowp = kS4 + j * 128 + tb;
    const float4 a = *(const float4*)(rowp + t0);
    const float4 c = *(const float4*)(rowp + s0);
    g00=fmaf(a.x,c.x,g00); g01=fmaf(a.x,c.y,g01); g02=fmaf(a.x,c.z,g02); g03=fmaf(a.x,c.w,g03);
    g10=fmaf(a.y,c.x,g10); g11=fmaf(a.y,c.y,g11); g12=fmaf(a.y,c.z,g12); g13=fmaf(a.y,c.w,g13);
    g20=fmaf(a.z,c.x,g20); g21=fmaf(a.z,c.y,g21); g22=fmaf(a.z,c.z,g22); g23=fmaf(a.z,c.w,g23);
    g30=fmaf(a.w,c.x,g30); g31=fmaf(a.w,c.y,g31); g32=fmaf(a.w,c.z,g32); g33=fmaf(a.w,c.w,g33);
  }
  const float4 it = *(const float4*)(inv_all + gb + tb + t0);
  const float4 is = *(const float4*)(inv_all + gb + tb + s0);
  float* Go = Gg + ((size_t)b * NCH + g4 * 4 + w) * (CC * CC);
  float4 o;
  o.x=g00*it.x*is.x; o.y=g01*it.x*is.y; o.z=g02*it.x*is.z; o.w=g03*it.x*is.w;
  *(float4*)(Go + (t0+0)*CC + s0) = o;
  o.x=g10*it.y*is.x; o.y=g11*it.y*is.y; o.z=g12*it.y*is.z; o.w=g13*it.y*is.w;
  *(float4*)(Go + (t0+1)*CC + s0) = o;
  o.x=g20*it.z*is.x; o.y=g21*it.z*is.y; o.z=g22*it.z*is.z; o.w=g23*it.z*is.w;
  *(float4*)(Go + (t0+2)*CC + s0) = o;
  o.x=g30*it.w*is.x; o.y=g31*it.w*is.y; o.z=g32*it.w*is.z; o.w=g33*it.w*is.w;
  *(float4*)(Go + (t0+3)*CC + s0) = o;
}

// ---------- Kernel 3: chunked gated delta scan, 3 barriers/chunk ----------
// wave 0: serial gate core (B, 16-token slices) + staging; waves 1-2: helpers
// (2 M rows x 16 cols per lane). G/thr2/inv read via uniform s_load (SMEM pipe).
__global__ __launch_bounds__(192, 1) void scan7(
    const float* __restrict__ kallT, const float* __restrict__ thr2_all,
    const float* __restrict__ inv_all, const float* __restrict__ Gg,
    float* __restrict__ readv)
{
  __shared__ float kS[3][CC * 68];   // raw k chunks [t][feature]
  __shared__ float rS[CC * 64];      // err0 = k - (M k)*inv  per feature
  __shared__ float cstS[CC * 64];    // gated raw err

  const int b = blockIdx.x, tid = threadIdx.x;
  const int w = tid >> 6, l = tid & 63;
  const int A = l >> 2, B4 = l & 3;
  const int r0 = 32 * (w - 1) + 2 * A;   // helper feature rows (w>0)
  const int jb = 16 * B4;
  const size_t gbase = (size_t)b * LSEQ;

  float M0[16], M1[16], acc[32];
  #pragma unroll
  for (int q = 0; q < 16; ++q) { M0[q] = 0.f; M1[q] = 0.f; }

// A2: rS[t] = k_t - (M . k_t)*inv_t  for t in [T0,T0+16), helper waves
#define A2_SLICE(KB, IVP, T0) do {                                             \
    _Pragma("unroll")                                                          \
    for (int t = (T0); t < (T0) + 16; ++t) {                                   \
      const float* kr = &kS[KB][t * 68 + jb];                                  \
      float p0a=0.f,p0b=0.f,p1a=0.f,p1b=0.f;                                   \
      _Pragma("unroll")                                                        \
      for (int q2 = 0; q2 < 4; ++q2) {                                         \
        const float4 kv = ((const float4*)kr)[q2];                             \
        p0a = fmaf(M0[4*q2+0], kv.x, p0a); p0b = fmaf(M0[4*q2+1], kv.y, p0b);  \
        p0a = fmaf(M0[4*q2+2], kv.z, p0a); p0b = fmaf(M0[4*q2+3], kv.w, p0b);  \
        p1a = fmaf(M1[4*q2+0], kv.x, p1a); p1b = fmaf(M1[4*q2+1], kv.y, p1b);  \
        p1a = fmaf(M1[4*q2+2], kv.z, p1a); p1b = fmaf(M1[4*q2+3], kv.w, p1b);  \
      }                                                                        \
      float p0 = quad_sum(p0a + p0b);                                          \
      float p1 = quad_sum(p1a + p1b);                                          \
      const float iv = (IVP)[t];                     /* uniform -> s_load */   \
      const float2 kv2 = *(const float2*)&kS[KB][t * 68 + r0];                 \
      if (B4 == 0)                                                             \
        *(float2*)&rS[t * 64 + r0] = make_float2(kv2.x - p0 * iv,              \
                                                 kv2.y - p1 * iv);             \
    }                                                                          \
  } while (0)

// C: M += (cstS[s]*inv[s]) (x) k_s for s in [S0,S0+16), helper waves
#define C_SLICE(KB, IVP, S0) do {                                              \
    _Pragma("unroll")                                                          \
    for (int s = (S0); s < (S0) + 16; ++s) {                                   \
      const float2 cc2 = *(const float2*)&cstS[s * 64 + r0];                   \
      const float iv = (IVP)[s];                     /* uniform -> s_load */   \
      const float c0 = cc2.x * iv, c1 = cc2.y * iv;                            \
      const float* kr = &kS[KB][s * 68 + jb];                                  \
      _Pragma("unroll")                                                        \
      for (int q2 = 0; q2 < 4; ++q2) {                                         \
        const float4 kv = ((const float4*)kr)[q2];                             \
        M0[4*q2+0] = fmaf(c0, kv.x, M0[4*q2+0]); M0[4*q2+1] = fmaf(c0, kv.y, M0[4*q2+1]); \
        M0[4*q2+2] = fmaf(c0, kv.z, M0[4*q2+2]); M0[4*q2+3] = fmaf(c0, kv.w, M0[4*q2+3]); \
        M1[4*q2+0] = fmaf(c1, kv.x, M1[4*q2+0]); M1[4*q2+1] = fmaf(c1, kv.y, M1[4*q2+1]); \
        M1[4*q2+2] = fmaf(c1, kv.z, M1[4*q2+2]); M1[4*q2+3] = fmaf(c1, kv.w, M1[4*q2+3]); \
      }                                                                        \
    }                                                                          \
  } while (0)

// B: serial gate core, tokens [16Q,16Q+16); G rows + thr2 via uniform s_load;
// triangular acc update (u > t only).
#define B_SLICE(Q, GROW, THP, LASTCH) do {                                     \
    const int t0_ = 16 * (Q);                                                  \
    _Pragma("unroll")                                                          \
    for (int i = 0; i < 16; ++i) acc[t0_ + i] += rS[(t0_ + i) * 64 + l];       \
    _Pragma("unroll")                                                          \
    for (int i = 0; i < 16; ++i) {                                             \
      const int t = t0_ + i;                                                   \
      const float* grow = (GROW) + t * CC;            /* uniform -> s_load */  \
      const float err = acc[t];                                                \
      const float ne2 = wave_sum(err * err);                                   \
      bool gate = (ne2 >= (THP)[t]);                                           \
      if ((LASTCH) && t == CC - 1) gate = false;                               \
      const float c = gate ? err : 0.f;                                        \
      cstS[t * 64 + l] = c;                                                    \
      _Pragma("unroll")                                                        \
      for (int u = t + 1; u < CC; ++u) acc[u] = fmaf(-grow[u], c, acc[u]);     \
    }                                                                          \
  } while (0)

  // ---- prologue: stage chunk 0 ----
  if (w < 2) {
    const float* src = kallT + (size_t)l * NT + gbase + w * 16;
    #pragma unroll
    for (int q = 0; q < 4; ++q) {
      const float4 v = ((const float4*)src)[q];
      const int t0 = w * 16 + q * 4;
      kS[0][(t0+0)*68 + l] = v.x; kS[0][(t0+1)*68 + l] = v.y;
      kS[0][(t0+2)*68 + l] = v.z; kS[0][(t0+3)*68 + l] = v.w;
    }
  }
  __syncthreads();

  for (int ch = 0; ch < NCH; ++ch) {
    const int cb = ch % 3, pb = (ch + 2) % 3, nb = (ch + 1) % 3;
    const bool lastch = (ch == NCH - 1);
    const float* ivcur = inv_all  + gbase + ch * CC;
    const float* ivprv = inv_all  + gbase + (ch - 1) * CC;
    const float* thcur = thr2_all + gbase + ch * CC;
    const float* Grow  = Gg + ((size_t)b * NCH + ch) * (CC * CC);

    // ---- P0: wave0 zero acc + stage k(ch+1); helpers C(ch-1) tail + A2(ch) 0..16
    if (w == 0) {
      #pragma unroll
      for (int u = 0; u < 32; ++u) acc[u] = 0.f;
      if (!lastch) {
        const float* src = kallT + (size_t)l * NT + gbase + (ch + 1) * CC;
        #pragma unroll
        for (int q = 0; q < 8; ++q) {
          const float4 v = ((const float4*)src)[q];
          const int t0 = q * 4;
          kS[nb][(t0+0)*68 + l] = v.x; kS[nb][(t0+1)*68 + l] = v.y;
          kS[nb][(t0+2)*68 + l] = v.z; kS[nb][(t0+3)*68 + l] = v.w;
        }
      }
    } else {
      if (ch > 0) C_SLICE(pb, ivprv, 16);
      A2_SLICE(cb, ivcur, 0);
    }
    __syncthreads();

    // ---- P1: B tokens 0..16 ; helpers A2(ch) 16..32 ----
    if (w == 0) B_SLICE(0, Grow, thcur, lastch);
    else        A2_SLICE(cb, ivcur, 16);
    __syncthreads();

    // ---- P2: B tokens 16..32 ; helpers C(ch) 0..16 ----
    if (w == 0) B_SLICE(1, Grow, thcur, lastch);
    else        C_SLICE(cb, ivcur, 0);
    __syncthreads();
  }

  // ---- epilogue: helpers C(31) tail + final read = M . k[1023] ----
  if (w > 0) {
    constexpr int fb = (NCH - 1) % 3;   // = 1
    const float* iv31 = inv_all + gbase + (NCH - 1) * CC;
    C_SLICE(fb, iv31, 16);
    const float* kr = &kS[fb][(CC - 1) * 68 + jb];
    float p0a=0.f,p0b=0.f,p1a=0.f,p1b=0.f;
    #pragma unroll
    for (int q2 = 0; q2 < 4; ++q2) {
      const float4 kv = ((const float4*)kr)[q2];
      p0a = fmaf(M0[4*q2+0], kv.x, p0a); p0b = fmaf(M0[4*q2+1], kv.y, p0b);
      p0a = fmaf(M0[4*q2+2], kv.z, p0a); p0b = fmaf(M0[4*q2+3], kv.w, p0b);
      p1a = fmaf(M1[4*q2+0], kv.x, p1a); p1b = fmaf(M1[4*q2+1], kv.y, p1b);
      p1a = fmaf(M1[4*q2+2], kv.z, p1a); p1b = fmaf(M1[4*q2+3], kv.w, p1b);
    }
    float d0 = quad_sum(p0a + p0b);
    float d1 = quad_sum(p1a + p1b);
    if (B4 == 0) *(float2*)&readv[b * 64 + r0] = make_float2(d0, d1);
  }
#undef A2_SLICE
#undef C_SLICE
#undef B_SLICE
}

// ---------- Kernel 4: r2T[i][b] = (read @ rpW + rpb)^T ----------
__global__ __launch_bounds__(64) void rproj_kernel(const float* __restrict__ readv,
    const float* __restrict__ rpW, const float* __restrict__ rpb, float* __restrict__ r2T)
{
  const int b = blockIdx.x, i = threadIdx.x;
  const float* rv = readv + b * 64;
  float acc = rpb[i];
  #pragma unroll
  for (int j = 0; j < 64; ++j)
    acc = fmaf(rv[j], rpW[j * 64 + i], acc);
  r2T[i * 64 + b] = acc;
}

// ---------- Kernel 5: out = r2 @ outW + outb ----------
__global__ __launch_bounds__(256, 1) void out_kernel(const float* __restrict__ r2T,
    const float* __restrict__ outW, const float* __restrict__ outb,
    float* __restrict__ out)
{
  const int v = blockIdx.x * 256 + threadIdx.x;
  float acc[64];
  #pragma unroll
  for (int b = 0; b < 64; ++b) acc[b] = 0.f;
  for (int k = 0; k < 64; ++k) {
    const float wv = outW[(size_t)k * NV + v];
    const float* rr = r2T + k * 64;           // uniform row -> s_load
    #pragma unroll
    for (int b = 0; b < 64; ++b)
      acc[b] = fmaf(rr[b], wv, acc[b]);
  }
  const float ob = outb[v];
  #pragma unroll
  for (int b = 0; b < 64; ++b)
    out[(size_t)b * NV + v] = acc[b] + ob;
}

extern "C" void kernel_launch(void* const* d_in, const int* in_sizes, int n_in,
                              void* d_out, int out_size, void* d_ws, size_t ws_size,
                              hipStream_t stream)
{
  const int*   seq   = (const int*)d_in[0];
  const float* embed = (const float*)d_in[1];
  const float* W1    = (const float*)d_in[2];
  const float* b1    = (const float*)d_in[3];
  const float* W2    = (const float*)d_in[4];
  const float* b2    = (const float*)d_in[5];
  const float* gam   = (const float*)d_in[6];
  const float* bet   = (const float*)d_in[7];
  const float* kpW   = (const float*)d_in[8];
  const float* rpW   = (const float*)d_in[9];
  const float* rpb   = (const float*)d_in[10];
  const float* outW  = (const float*)d_in[11];
  const float* outb  = (const float*)d_in[12];
  float* out = (float*)d_out;

  float* ws = (float*)d_ws;
  float* kallT = ws;                                    // 4,194,304 f  [feat][tok]
  float* G     = kallT + (size_t)HDIM * NT;             // 2,097,152 f
  float* thr2  = G     + (size_t)NB * NCH * CC * CC;    //    65,536 f
  float* inv   = thr2  + NT;                            //    65,536 f
  float* readv = inv   + NT;                            //     4,096 f
  float* r2T   = readv + NB * HDIM;                     //     4,096 f
  float* W1T   = r2T   + NB * HDIM;                     //     8,192 f
  float* kpWT  = W1T   + 8192;                          //     4,096 f

  hipLaunchKernelGGL(transpose_w, dim3(48), dim3(256), 0, stream, W1, kpW, W1T, kpWT);
  hipLaunchKernelGGL(tok4, dim3(256), dim3(256), 0, stream,
                     seq, embed, W1T, b1, W2, b2, gam, bet, kpWT, kallT, thr2, inv);
  hipLaunchKernelGGL(gram3, dim3(NB * 8), dim3(256), 0, stream, kallT, inv, G);
  hipLaunchKernelGGL(scan7, dim3(NB), dim3(192), 0, stream, kallT, thr2, inv, G, readv);
  hipLaunchKernelGGL(rproj_kernel, dim3(NB), dim3(64), 0, stream, readv, rpW, rpb, r2T);
  hipLaunchKernelGGL(out_kernel, dim3(NV / 256), dim3(256), 0, stream, r2T, outW, outb, out);
}

// Round 8
// 535.231 us; speedup vs baseline: 1.1675x; 1.1675x over previous
//
#include <hip/hip_runtime.h>
#include <hip/hip_bf16.h>

#define HDIM 64
#define LSEQ 1024
#define NB 64
#define NV 32000
#define CC 32            // chunk length
#define NCH 32           // chunks per sequence
#define NT (NB * LSEQ)   // total tokens = kallT row stride

// ---------- DPP cross-lane sums (pure VALU) ----------
template<int CTRL>
__device__ __forceinline__ float dpp_red(float x) {
  int y = __builtin_amdgcn_update_dpp(0, __float_as_int(x), CTRL, 0xF, 0xF, true);
  return x + __int_as_float(y);
}
__device__ __forceinline__ float quad_sum(float x) {
  x = dpp_red<0xB1>(x);    // xor 1
  x = dpp_red<0x4E>(x);    // xor 2
  return x;
}
__device__ __forceinline__ float wave_sum(float x) {
  x = dpp_red<0xB1>(x);
  x = dpp_red<0x4E>(x);
  x = dpp_red<0x141>(x);   // row_half_mirror -> sum of 8
  x = dpp_red<0x140>(x);   // row_mirror      -> sum of 16
  float a = __int_as_float(__builtin_amdgcn_readlane(__float_as_int(x), 0));
  float b = __int_as_float(__builtin_amdgcn_readlane(__float_as_int(x), 16));
  float c = __int_as_float(__builtin_amdgcn_readlane(__float_as_int(x), 32));
  float d = __int_as_float(__builtin_amdgcn_readlane(__float_as_int(x), 48));
  return (a + b) + (c + d);
}

// ---------- Kernel 0: transpose W1 (64x128 -> 128x64) and kpW (64x64) ----------
__global__ __launch_bounds__(256) void transpose_w(const float* __restrict__ W1,
    const float* __restrict__ kpW, float* __restrict__ W1T, float* __restrict__ kpWT)
{
  const int tid = blockIdx.x * 256 + threadIdx.x;
  if (tid < 8192) { const int c = tid >> 6, j = tid & 63; W1T[tid] = W1[j * 128 + c]; }
  else { const int e = tid - 8192; const int i = e >> 6, j = e & 63; kpWT[e] = kpW[j * 64 + i]; }
}

// ---------- Kernel 1: token transform, TWO threads per token ----------
// 512 blocks x 256 threads: block owns 128 tokens; thread pair (tl, half)
// splits FF channels and k-proj outputs -> 2 blocks/CU, 2 waves/SIMD.
__global__ __launch_bounds__(256, 2) void tok5(
    const int* __restrict__ seq, const float* __restrict__ embed,
    const float* __restrict__ W1T, const float* __restrict__ b1,
    const float* __restrict__ W2, const float* __restrict__ b2,
    const float* __restrict__ gamma, const float* __restrict__ beta,
    const float* __restrict__ kpWT, float* __restrict__ kallT,
    float* __restrict__ thr2_all, float* __restrict__ inv_all)
{
  __shared__ float xs[64 * 128];    // [feature][token-local], reused for hn
  __shared__ float nks[128];
  const int tid = threadIdx.x;
  const int tl = tid & 127, half = tid >> 7;
  const int tok = blockIdx.x * 128 + tl;
  const int row = seq[tok];

  float h[64], x[64];
  const float4* ep = (const float4*)(embed + (size_t)row * HDIM);
  #pragma unroll
  for (int q = 0; q < 16; ++q) {
    const float4 v = ep[q];
    h[4*q] = v.x; h[4*q+1] = v.y; h[4*q+2] = v.z; h[4*q+3] = v.w;
  }
  if (half == 0) {
    #pragma unroll
    for (int j = 0; j < 64; ++j) x[j] = h[j] + b2[j];
  } else {
    #pragma unroll
    for (int j = 0; j < 64; ++j) x[j] = 0.f;
  }

  const int c0 = half * 64;
  for (int c = c0; c < c0 + 64; ++c) {
    const float* w1r = W1T + c * 64;                   // uniform row -> s_load
    float a0 = 0.f, a1 = 0.f, a2 = 0.f, a3 = 0.f;
    #pragma unroll
    for (int j = 0; j < 64; j += 4) {
      a0 = fmaf(h[j],   w1r[j],   a0);
      a1 = fmaf(h[j+1], w1r[j+1], a1);
      a2 = fmaf(h[j+2], w1r[j+2], a2);
      a3 = fmaf(h[j+3], w1r[j+3], a3);
    }
    const float y = fmaxf(b1[c] + ((a0 + a1) + (a2 + a3)), 0.f);
    const float* w2r = W2 + c * 64;
    #pragma unroll
    for (int j = 0; j < 64; ++j) x[j] = fmaf(y, w2r[j], x[j]);
  }

  // combine halves of x
  if (half == 1) {
    #pragma unroll
    for (int j = 0; j < 64; ++j) xs[j * 128 + tl] = x[j];
  }
  __syncthreads();
  if (half == 0) {
    #pragma unroll
    for (int j = 0; j < 64; ++j) x[j] += xs[j * 128 + tl];
    // layernorm
    float s0=0.f,s1=0.f,s2=0.f,s3=0.f,q0=0.f,q1=0.f,q2=0.f,q3=0.f;
    #pragma unroll
    for (int j = 0; j < 64; j += 4) {
      s0 += x[j]; s1 += x[j+1]; s2 += x[j+2]; s3 += x[j+3];
      q0 = fmaf(x[j],   x[j],   q0); q1 = fmaf(x[j+1], x[j+1], q1);
      q2 = fmaf(x[j+2], x[j+2], q2); q3 = fmaf(x[j+3], x[j+3], q3);
    }
    const float mu  = ((s0+s1)+(s2+s3)) * (1.f/64.f);
    const float var = ((q0+q1)+(q2+q3)) * (1.f/64.f) - mu * mu;
    const float rs  = rsqrtf(var + 1e-5f);
    #pragma unroll
    for (int j = 0; j < 64; ++j) {
      h[j] = (x[j] - mu) * rs * gamma[j] + beta[j];
      xs[j * 128 + tl] = h[j];
    }
  }
  __syncthreads();
  if (half == 1) {
    #pragma unroll
    for (int j = 0; j < 64; ++j) h[j] = xs[j * 128 + tl];
  }

  // k projection, own half of outputs
  float nk2 = 0.f;
  const int i0 = half * 32;
  #pragma unroll 2
  for (int i = i0; i < i0 + 32; ++i) {
    const float* kr = kpWT + i * 64;                   // uniform row -> s_load
    float c0_=0.f,c1_=0.f,c2_=0.f,c3_=0.f;
    #pragma unroll
    for (int j = 0; j < 64; j += 4) {
      c0_ = fmaf(h[j],   kr[j],   c0_);
      c1_ = fmaf(h[j+1], kr[j+1], c1_);
      c2_ = fmaf(h[j+2], kr[j+2], c2_);
      c3_ = fmaf(h[j+3], kr[j+3], c3_);
    }
    const float ki = (c0_ + c1_) + (c2_ + c3_);
    nk2 = fmaf(ki, ki, nk2);
    kallT[(size_t)i * NT + tok] = ki;
  }
  if (half == 1) nks[tl] = nk2;
  __syncthreads();
  if (half == 0) {
    nk2 += nks[tl];
    thr2_all[tok] = 0.16f * nk2;
    inv_all[tok]  = 1.f / fmaxf(sqrtf(nk2), 1e-12f);
  }
}

// ---------- Kernel 2: Gram, 4 chunks per block via LDS slab ----------
__global__ __launch_bounds__(256, 1) void gram3(const float* __restrict__ kallT,
    const float* __restrict__ inv_all, float* __restrict__ Gg)
{
  __shared__ float kS4[64 * 128];     // [feature][token-in-slab]
  const int bi = blockIdx.x;          // b*8 + g4
  const int b = bi >> 3, g4 = bi & 7;
  const int tid = threadIdx.x;
  const size_t gb = (size_t)b * LSEQ + g4 * 128;

  #pragma unroll
  for (int q = 0; q < 8; ++q) {
    const int e = q * 256 + tid;
    const int j = e >> 5, p = e & 31;
    ((float4*)kS4)[(j << 5) + p] =
        *(const float4*)(kallT + (size_t)j * NT + gb + p * 4);
  }
  __syncthreads();

  const int w = tid >> 6, l = tid & 63;
  const int tb = w * 32;
  const int t0 = (l & 7) * 4, s0 = (l >> 3) * 4;
  float g00=0,g01=0,g02=0,g03=0, g10=0,g11=0,g12=0,g13=0;
  float g20=0,g21=0,g22=0,g23=0, g30=0,g31=0,g32=0,g33=0;
  #pragma unroll 8
  for (int j = 0; j < 64; ++j) {
    const float* rowp = kS4 + j * 128 + tb;
    const float4 a = *(const float4*)(rowp + t0);
    const float4 c = *(const float4*)(rowp + s0);
    g00=fmaf(a.x,c.x,g00); g01=fmaf(a.x,c.y,g01); g02=fmaf(a.x,c.z,g02); g03=fmaf(a.x,c.w,g03);
    g10=fmaf(a.y,c.x,g10); g11=fmaf(a.y,c.y,g11); g12=fmaf(a.y,c.z,g12); g13=fmaf(a.y,c.w,g13);
    g20=fmaf(a.z,c.x,g20); g21=fmaf(a.z,c.y,g21); g22=fmaf(a.z,c.z,g22); g23=fmaf(a.z,c.w,g23);
    g30=fmaf(a.w,c.x,g30); g31=fmaf(a.w,c.y,g31); g32=fmaf(a.w,c.z,g32); g33=fmaf(a.w,c.w,g33);
  }
  const float4 it = *(const float4*)(inv_all + gb + tb + t0);
  const float4 is = *(const float4*)(inv_all + gb + tb + s0);
  float* Go = Gg + ((size_t)b * NCH + g4 * 4 + w) * (CC * CC);
  float4 o;
  o.x=g00*it.x*is.x; o.y=g01*it.x*is.y; o.z=g02*it.x*is.z; o.w=g03*it.x*is.w;
  *(float4*)(Go + (t0+0)*CC + s0) = o;
  o.x=g10*it.y*is.x; o.y=g11*it.y*is.y; o.z=g12*it.y*is.z; o.w=g13*it.y*is.w;
  *(float4*)(Go + (t0+1)*CC + s0) = o;
  o.x=g20*it.z*is.x; o.y=g21*it.z*is.y; o.z=g22*it.z*is.z; o.w=g23*it.z*is.w;
  *(float4*)(Go + (t0+2)*CC + s0) = o;
  o.x=g30*it.w*is.x; o.y=g31*it.w*is.y; o.z=g32*it.w*is.z; o.w=g33*it.w*is.w;
  *(float4*)(Go + (t0+3)*CC + s0) = o;
}

// ---------- Kernel 3: chunked gated delta scan ----------
// 3 barriers/chunk. wave 0: serial gate core (LDS G, triangular) + staging;
// waves 1-2: helpers (2 M rows x 16 cols per lane), inv via uniform s_load.
__global__ __launch_bounds__(192, 1) void scan8(
    const float* __restrict__ kallT, const float* __restrict__ thr2_all,
    const float* __restrict__ inv_all, const float* __restrict__ Gg,
    float* __restrict__ readv)
{
  __shared__ float kS[3][CC * 68];   // raw k chunks [t][feature]
  __shared__ float GS[2][CC * CC];   // normalized Gram, double-buffered
  __shared__ float rS[CC * 64];      // err0 = k - (M k)*inv per feature
  __shared__ float cstS[CC * 64];    // gated raw err

  const int b = blockIdx.x, tid = threadIdx.x;
  const int w = tid >> 6, l = tid & 63;
  const int A = l >> 2, B4 = l & 3;
  const int r0 = 32 * (w - 1) + 2 * A;   // helper feature rows (w>0)
  const int jb = 16 * B4;
  const size_t gbase = (size_t)b * LSEQ;

  float M0[16], M1[16], acc[32];
  #pragma unroll
  for (int q = 0; q < 16; ++q) { M0[q] = 0.f; M1[q] = 0.f; }

// A2: rS[t] = k_t - (M . k_t)*inv_t for t in [T0,T0+16), helper waves
#define A2_SLICE(KB, IVP, T0) do {                                             \
    _Pragma("unroll")                                                          \
    for (int t = (T0); t < (T0) + 16; ++t) {                                   \
      const float* kr = &kS[KB][t * 68 + jb];                                  \
      float p0a=0.f,p0b=0.f,p1a=0.f,p1b=0.f;                                   \
      _Pragma("unroll")                                                        \
      for (int q2 = 0; q2 < 4; ++q2) {                                         \
        const float4 kv = ((const float4*)kr)[q2];                             \
        p0a = fmaf(M0[4*q2+0], kv.x, p0a); p0b = fmaf(M0[4*q2+1], kv.y, p0b);  \
        p0a = fmaf(M0[4*q2+2], kv.z, p0a); p0b = fmaf(M0[4*q2+3], kv.w, p0b);  \
        p1a = fmaf(M1[4*q2+0], kv.x, p1a); p1b = fmaf(M1[4*q2+1], kv.y, p1b);  \
        p1a = fmaf(M1[4*q2+2], kv.z, p1a); p1b = fmaf(M1[4*q2+3], kv.w, p1b);  \
      }                                                                        \
      float p0 = quad_sum(p0a + p0b);                                          \
      float p1 = quad_sum(p1a + p1b);                                          \
      const float iv = (IVP)[t];                     /* uniform -> s_load */   \
      const float2 kv2 = *(const float2*)&kS[KB][t * 68 + r0];                 \
      if (B4 == 0)                                                             \
        *(float2*)&rS[t * 64 + r0] = make_float2(kv2.x - p0 * iv,              \
                                                 kv2.y - p1 * iv);             \
    }                                                                          \
  } while (0)

// C: M += (cstS[s]*inv[s]) (x) k_s for s in [S0,S0+16), helper waves
#define C_SLICE(KB, IVP, S0) do {                                              \
    _Pragma("unroll")                                                          \
    for (int s = (S0); s < (S0) + 16; ++s) {                                   \
      const float2 cc2 = *(const float2*)&cstS[s * 64 + r0];                   \
      const float iv = (IVP)[s];                     /* uniform -> s_load */   \
      const float c0 = cc2.x * iv, c1 = cc2.y * iv;                            \
      const float* kr = &kS[KB][s * 68 + jb];                                  \
      _Pragma("unroll")                                                        \
      for (int q2 = 0; q2 < 4; ++q2) {                                         \
        const float4 kv = ((const float4*)kr)[q2];                             \
        M0[4*q2+0] = fmaf(c0, kv.x, M0[4*q2+0]); M0[4*q2+1] = fmaf(c0, kv.y, M0[4*q2+1]); \
        M0[4*q2+2] = fmaf(c0, kv.z, M0[4*q2+2]); M0[4*q2+3] = fmaf(c0, kv.w, M0[4*q2+3]); \
        M1[4*q2+0] = fmaf(c1, kv.x, M1[4*q2+0]); M1[4*q2+1] = fmaf(c1, kv.y, M1[4*q2+1]); \
        M1[4*q2+2] = fmaf(c1, kv.z, M1[4*q2+2]); M1[4*q2+3] = fmaf(c1, kv.w, M1[4*q2+3]); \
      }                                                                        \
    }                                                                          \
  } while (0)

// B: serial gate core, tokens [16Q,16Q+16); G rows from LDS (triangular,
// compile-time quad bounds); thr2 via hoistable uniform s_load.
#define B_SLICE(Q, GSB, THP, LASTCH) do {                                      \
    const int t0_ = 16 * (Q);                                                  \
    _Pragma("unroll")                                                          \
    for (int i = 0; i < 16; ++i) acc[t0_ + i] += rS[(t0_ + i) * 64 + l];       \
    _Pragma("unroll")                                                          \
    for (int i = 0; i < 16; ++i) {                                             \
      const int t = t0_ + i;                                                   \
      float g[32];                                                             \
      {                                                                        \
        const float4* gp = (const float4*)&GS[GSB][t * CC];                    \
        _Pragma("unroll")                                                      \
        for (int r = (t + 1) >> 2; r < 8; ++r) {                               \
          const float4 v = gp[r];                                              \
          g[4*r]=v.x; g[4*r+1]=v.y; g[4*r+2]=v.z; g[4*r+3]=v.w;                \
        }                                                                      \
      }                                                                        \
      const float err = acc[t];                                                \
      const float ne2 = wave_sum(err * err);                                   \
      bool gate = (ne2 >= (THP)[t]);                                           \
      if ((LASTCH) && t == CC - 1) gate = false;                               \
      const float c = gate ? err : 0.f;                                        \
      cstS[t * 64 + l] = c;                                                    \
      _Pragma("unroll")                                                        \
      for (int u = t + 1; u < CC; ++u) acc[u] = fmaf(-g[u], c, acc[u]);        \
    }                                                                          \
  } while (0)

  // ---- prologue: stage chunk 0 (waves 0,1) + G chunk 0 (wave 2) ----
  if (w < 2) {
    const float* src = kallT + (size_t)l * NT + gbase + w * 16;
    #pragma unroll
    for (int q = 0; q < 4; ++q) {
      const float4 v = ((const float4*)src)[q];
      const int t0 = w * 16 + q * 4;
      kS[0][(t0+0)*68 + l] = v.x; kS[0][(t0+1)*68 + l] = v.y;
      kS[0][(t0+2)*68 + l] = v.z; kS[0][(t0+3)*68 + l] = v.w;
    }
  } else {
    const float4* gsrc = (const float4*)(Gg + (size_t)b * NCH * (CC * CC));
    #pragma unroll
    for (int q = 0; q < 4; ++q) ((float4*)GS[0])[q * 64 + l] = gsrc[q * 64 + l];
  }
  __syncthreads();

  for (int ch = 0; ch < NCH; ++ch) {
    const int cb = ch % 3, pb = (ch + 2) % 3, nb = (ch + 1) % 3;
    const int cg = ch & 1, ng = 1 - cg;
    const bool lastch = (ch == NCH - 1);
    const float* ivcur = inv_all  + gbase + ch * CC;
    const float* ivprv = inv_all  + gbase + (ch - 1) * CC;
    const float* thcur = thr2_all + gbase + ch * CC;

    // ---- P0: wave0 zero acc + stage k(ch+1), G(ch+1); helpers C(ch-1) tail + A2 0..16
    if (w == 0) {
      #pragma unroll
      for (int u = 0; u < 32; ++u) acc[u] = 0.f;
      if (!lastch) {
        const float* src = kallT + (size_t)l * NT + gbase + (ch + 1) * CC;
        #pragma unroll
        for (int q = 0; q < 8; ++q) {
          const float4 v = ((const float4*)src)[q];
          const int t0 = q * 4;
          kS[nb][(t0+0)*68 + l] = v.x; kS[nb][(t0+1)*68 + l] = v.y;
          kS[nb][(t0+2)*68 + l] = v.z; kS[nb][(t0+3)*68 + l] = v.w;
        }
        const float4* gsrc = (const float4*)(Gg + ((size_t)b * NCH + ch + 1) * (CC * CC));
        #pragma unroll
        for (int q = 0; q < 4; ++q) ((float4*)GS[ng])[q * 64 + l] = gsrc[q * 64 + l];
      }
    } else {
      if (ch > 0) C_SLICE(pb, ivprv, 16);
      A2_SLICE(cb, ivcur, 0);
    }
    __syncthreads();

    // ---- P1: B tokens 0..16 ; helpers A2 16..32 ----
    if (w == 0) B_SLICE(0, cg, thcur, lastch);
    else        A2_SLICE(cb, ivcur, 16);
    __syncthreads();

    // ---- P2: B tokens 16..32 ; helpers C(ch) 0..16 ----
    if (w == 0) B_SLICE(1, cg, thcur, lastch);
    else        C_SLICE(cb, ivcur, 0);
    __syncthreads();
  }

  // ---- epilogue: helpers C(31) tail + final read = M . k[1023] ----
  if (w > 0) {
    constexpr int fb = (NCH - 1) % 3;   // = 1
    const float* iv31 = inv_all + gbase + (NCH - 1) * CC;
    C_SLICE(fb, iv31, 16);
    const float* kr = &kS[fb][(CC - 1) * 68 + jb];
    float p0a=0.f,p0b=0.f,p1a=0.f,p1b=0.f;
    #pragma unroll
    for (int q2 = 0; q2 < 4; ++q2) {
      const float4 kv = ((const float4*)kr)[q2];
      p0a = fmaf(M0[4*q2+0], kv.x, p0a); p0b = fmaf(M0[4*q2+1], kv.y, p0b);
      p0a = fmaf(M0[4*q2+2], kv.z, p0a); p0b = fmaf(M0[4*q2+3], kv.w, p0b);
      p1a = fmaf(M1[4*q2+0], kv.x, p1a); p1b = fmaf(M1[4*q2+1], kv.y, p1b);
      p1a = fmaf(M1[4*q2+2], kv.z, p1a); p1b = fmaf(M1[4*q2+3], kv.w, p1b);
    }
    float d0 = quad_sum(p0a + p0b);
    float d1 = quad_sum(p1a + p1b);
    if (B4 == 0) *(float2*)&readv[b * 64 + r0] = make_float2(d0, d1);
  }
#undef A2_SLICE
#undef C_SLICE
#undef B_SLICE
}

// ---------- Kernel 4: r2T[i][b] = (read @ rpW + rpb)^T ----------
__global__ __launch_bounds__(64) void rproj_kernel(const float* __restrict__ readv,
    const float* __restrict__ rpW, const float* __restrict__ rpb, float* __restrict__ r2T)
{
  const int b = blockIdx.x, i = threadIdx.x;
  const float* rv = readv + b * 64;
  float acc = rpb[i];
  #pragma unroll
  for (int j = 0; j < 64; ++j)
    acc = fmaf(rv[j], rpW[j * 64 + i], acc);
  r2T[i * 64 + b] = acc;
}

// ---------- Kernel 5: out = r2 @ outW + outb ----------
__global__ __launch_bounds__(256, 1) void out_kernel(const float* __restrict__ r2T,
    const float* __restrict__ outW, const float* __restrict__ outb,
    float* __restrict__ out)
{
  const int v = blockIdx.x * 256 + threadIdx.x;
  float acc[64];
  #pragma unroll
  for (int b = 0; b < 64; ++b) acc[b] = 0.f;
  for (int k = 0; k < 64; ++k) {
    const float wv = outW[(size_t)k * NV + v];
    const float* rr = r2T + k * 64;           // uniform row -> s_load
    #pragma unroll
    for (int b = 0; b < 64; ++b)
      acc[b] = fmaf(rr[b], wv, acc[b]);
  }
  const float ob = outb[v];
  #pragma unroll
  for (int b = 0; b < 64; ++b)
    out[(size_t)b * NV + v] = acc[b] + ob;
}

extern "C" void kernel_launch(void* const* d_in, const int* in_sizes, int n_in,
                              void* d_out, int out_size, void* d_ws, size_t ws_size,
                              hipStream_t stream)
{
  const int*   seq   = (const int*)d_in[0];
  const float* embed = (const float*)d_in[1];
  const float* W1    = (const float*)d_in[2];
  const float* b1    = (const float*)d_in[3];
  const float* W2    = (const float*)d_in[4];
  const float* b2    = (const float*)d_in[5];
  const float* gam   = (const float*)d_in[6];
  const float* bet   = (const float*)d_in[7];
  const float* kpW   = (const float*)d_in[8];
  const float* rpW   = (const float*)d_in[9];
  const float* rpb   = (const float*)d_in[10];
  const float* outW  = (const float*)d_in[11];
  const float* outb  = (const float*)d_in[12];
  float* out = (float*)d_out;

  float* ws = (float*)d_ws;
  float* kallT = ws;                                    // 4,194,304 f  [feat][tok]
  float* G     = kallT + (size_t)HDIM * NT;             // 2,097,152 f
  float* thr2  = G     + (size_t)NB * NCH * CC * CC;    //    65,536 f
  float* inv   = thr2  + NT;                            //    65,536 f
  float* readv = inv   + NT;                            //     4,096 f
  float* r2T   = readv + NB * HDIM;                     //     4,096 f
  float* W1T   = r2T   + NB * HDIM;                     //     8,192 f
  float* kpWT  = W1T   + 8192;                          //     4,096 f

  hipLaunchKernelGGL(transpose_w, dim3(48), dim3(256), 0, stream, W1, kpW, W1T, kpWT);
  hipLaunchKernelGGL(tok5, dim3(NT / 128), dim3(256), 0, stream,
                     seq, embed, W1T, b1, W2, b2, gam, bet, kpWT, kallT, thr2, inv);
  hipLaunchKernelGGL(gram3, dim3(NB * 8), dim3(256), 0, stream, kallT, inv, G);
  hipLaunchKernelGGL(scan8, dim3(NB), dim3(192), 0, stream, kallT, thr2, inv, G, readv);
  hipLaunchKernelGGL(rproj_kernel, dim3(NB), dim3(64), 0, stream, readv, rpW, rpb, r2T);
  hipLaunchKernelGGL(out_kernel, dim3(NV / 256), dim3(256), 0, stream, r2T, outW, outb, out);
}

// Round 9
// 498.638 us; speedup vs baseline: 1.2532x; 1.0734x over previous
//
#include <hip/hip_runtime.h>
#include <hip/hip_bf16.h>

#define HDIM 64
#define LSEQ 1024
#define NB 64
#define NV 32000
#define CC 32            // chunk length
#define NCH 32           // chunks per sequence
#define NT (NB * LSEQ)   // total tokens = kallT row stride

// ---------- DPP cross-lane sums (pure VALU) ----------
template<int CTRL>
__device__ __forceinline__ float dpp_red(float x) {
  int y = __builtin_amdgcn_update_dpp(0, __float_as_int(x), CTRL, 0xF, 0xF, true);
  return x + __int_as_float(y);
}
__device__ __forceinline__ float quad_sum(float x) {
  x = dpp_red<0xB1>(x);    // xor 1
  x = dpp_red<0x4E>(x);    // xor 2
  return x;
}
__device__ __forceinline__ float wave_sum(float x) {
  x = dpp_red<0xB1>(x);
  x = dpp_red<0x4E>(x);
  x = dpp_red<0x141>(x);   // row_half_mirror -> sum of 8
  x = dpp_red<0x140>(x);   // row_mirror      -> sum of 16
  float a = __int_as_float(__builtin_amdgcn_readlane(__float_as_int(x), 0));
  float b = __int_as_float(__builtin_amdgcn_readlane(__float_as_int(x), 16));
  float c = __int_as_float(__builtin_amdgcn_readlane(__float_as_int(x), 32));
  float d = __int_as_float(__builtin_amdgcn_readlane(__float_as_int(x), 48));
  return (a + b) + (c + d);
}

// ---------- Kernel 0: transpose W1 (64x128 -> 128x64) and kpW (64x64) ----------
__global__ __launch_bounds__(256) void transpose_w(const float* __restrict__ W1,
    const float* __restrict__ kpW, float* __restrict__ W1T, float* __restrict__ kpWT)
{
  const int tid = blockIdx.x * 256 + threadIdx.x;
  if (tid < 8192) { const int c = tid >> 6, j = tid & 63; W1T[tid] = W1[j * 128 + c]; }
  else { const int e = tid - 8192; const int i = e >> 6, j = e & 63; kpWT[e] = kpW[j * 64 + i]; }
}

// ---------- Kernel 1: token transform, lane = token (R6 tok4, known-good) ----------
__global__ __launch_bounds__(256, 1) void tok4(
    const int* __restrict__ seq, const float* __restrict__ embed,
    const float* __restrict__ W1T, const float* __restrict__ b1,
    const float* __restrict__ W2, const float* __restrict__ b2,
    const float* __restrict__ gamma, const float* __restrict__ beta,
    const float* __restrict__ kpWT, float* __restrict__ kallT,
    float* __restrict__ thr2_all, float* __restrict__ inv_all)
{
  const int tok = blockIdx.x * 256 + threadIdx.x;
  const int row = seq[tok];
  float h[64], x[64];
  const float4* ep = (const float4*)(embed + (size_t)row * HDIM);
  #pragma unroll
  for (int q = 0; q < 16; ++q) {
    const float4 v = ep[q];
    h[4*q] = v.x; h[4*q+1] = v.y; h[4*q+2] = v.z; h[4*q+3] = v.w;
  }
  #pragma unroll
  for (int j = 0; j < 64; ++j) x[j] = h[j] + b2[j];

  for (int c = 0; c < 128; ++c) {
    const float* w1r = W1T + c * 64;                   // uniform row -> s_load
    float a0 = 0.f, a1 = 0.f, a2 = 0.f, a3 = 0.f;
    #pragma unroll
    for (int j = 0; j < 64; j += 4) {
      a0 = fmaf(h[j],   w1r[j],   a0);
      a1 = fmaf(h[j+1], w1r[j+1], a1);
      a2 = fmaf(h[j+2], w1r[j+2], a2);
      a3 = fmaf(h[j+3], w1r[j+3], a3);
    }
    const float y = fmaxf(b1[c] + ((a0 + a1) + (a2 + a3)), 0.f);
    const float* w2r = W2 + c * 64;
    #pragma unroll
    for (int j = 0; j < 64; ++j) x[j] = fmaf(y, w2r[j], x[j]);
  }

  float s0=0.f,s1=0.f,s2=0.f,s3=0.f,q0=0.f,q1=0.f,q2=0.f,q3=0.f;
  #pragma unroll
  for (int j = 0; j < 64; j += 4) {
    s0 += x[j]; s1 += x[j+1]; s2 += x[j+2]; s3 += x[j+3];
    q0 = fmaf(x[j],   x[j],   q0); q1 = fmaf(x[j+1], x[j+1], q1);
    q2 = fmaf(x[j+2], x[j+2], q2); q3 = fmaf(x[j+3], x[j+3], q3);
  }
  const float mu  = ((s0+s1)+(s2+s3)) * (1.f/64.f);
  const float var = ((q0+q1)+(q2+q3)) * (1.f/64.f) - mu * mu;
  const float rs  = rsqrtf(var + 1e-5f);
  #pragma unroll
  for (int j = 0; j < 64; ++j) h[j] = (x[j] - mu) * rs * gamma[j] + beta[j];

  float nk2 = 0.f;
  for (int i = 0; i < 64; ++i) {
    const float* kr = kpWT + i * 64;                   // uniform row -> s_load
    float c0=0.f,c1=0.f,c2=0.f,c3=0.f;
    #pragma unroll
    for (int j = 0; j < 64; j += 4) {
      c0 = fmaf(h[j],   kr[j],   c0);
      c1 = fmaf(h[j+1], kr[j+1], c1);
      c2 = fmaf(h[j+2], kr[j+2], c2);
      c3 = fmaf(h[j+3], kr[j+3], c3);
    }
    const float ki = (c0 + c1) + (c2 + c3);
    nk2 = fmaf(ki, ki, nk2);
    kallT[(size_t)i * NT + tok] = ki;
  }
  thr2_all[tok] = 0.16f * nk2;
  inv_all[tok]  = 1.f / fmaxf(sqrtf(nk2), 1e-12f);
}

// ---------- Kernel 2: Gram, 4 chunks per block via LDS slab ----------
__global__ __launch_bounds__(256, 1) void gram3(const float* __restrict__ kallT,
    const float* __restrict__ inv_all, float* __restrict__ Gg)
{
  __shared__ float kS4[64 * 128];     // [feature][token-in-slab]
  const int bi = blockIdx.x;          // b*8 + g4
  const int b = bi >> 3, g4 = bi & 7;
  const int tid = threadIdx.x;
  const size_t gb = (size_t)b * LSEQ + g4 * 128;

  #pragma unroll
  for (int q = 0; q < 8; ++q) {
    const int e = q * 256 + tid;
    const int j = e >> 5, p = e & 31;
    ((float4*)kS4)[(j << 5) + p] =
        *(const float4*)(kallT + (size_t)j * NT + gb + p * 4);
  }
  __syncthreads();

  const int w = tid >> 6, l = tid & 63;
  const int tb = w * 32;
  const int t0 = (l & 7) * 4, s0 = (l >> 3) * 4;
  float g00=0,g01=0,g02=0,g03=0, g10=0,g11=0,g12=0,g13=0;
  float g20=0,g21=0,g22=0,g23=0, g30=0,g31=0,g32=0,g33=0;
  #pragma unroll 8
  for (int j = 0; j < 64; ++j) {
    const float* rowp = kS4 + j * 128 + tb;
    const float4 a = *(const float4*)(rowp + t0);
    const float4 c = *(const float4*)(rowp + s0);
    g00=fmaf(a.x,c.x,g00); g01=fmaf(a.x,c.y,g01); g02=fmaf(a.x,c.z,g02); g03=fmaf(a.x,c.w,g03);
    g10=fmaf(a.y,c.x,g10); g11=fmaf(a.y,c.y,g11); g12=fmaf(a.y,c.z,g12); g13=fmaf(a.y,c.w,g13);
    g20=fmaf(a.z,c.x,g20); g21=fmaf(a.z,c.y,g21); g22=fmaf(a.z,c.z,g22); g23=fmaf(a.z,c.w,g23);
    g30=fmaf(a.w,c.x,g30); g31=fmaf(a.w,c.y,g31); g32=fmaf(a.w,c.z,g32); g33=fmaf(a.w,c.w,g33);
  }
  const float4 it = *(const float4*)(inv_all + gb + tb + t0);
  const float4 is = *(const float4*)(inv_all + gb + tb + s0);
  float* Go = Gg + ((size_t)b * NCH + g4 * 4 + w) * (CC * CC);
  float4 o;
  o.x=g00*it.x*is.x; o.y=g01*it.x*is.y; o.z=g02*it.x*is.z; o.w=g03*it.x*is.w;
  *(float4*)(Go + (t0+0)*CC + s0) = o;
  o.x=g10*it.y*is.x; o.y=g11*it.y*is.y; o.z=g12*it.y*is.z; o.w=g13*it.y*is.w;
  *(float4*)(Go + (t0+1)*CC + s0) = o;
  o.x=g20*it.z*is.x; o.y=g21*it.z*is.y; o.z=g22*it.z*is.z; o.w=g23*it.z*is.w;
  *(float4*)(Go + (t0+2)*CC + s0) = o;
  o.x=g30*it.w*is.x; o.y=g31*it.w*is.y; o.z=g32*it.w*is.z; o.w=g33*it.w*is.w;
  *(float4*)(Go + (t0+3)*CC + s0) = o;
}

// ---------- Kernel 3: chunked gated delta scan ----------
// 3 barriers/chunk. wave 0: serial gate core (LDS G, triangular, SW-pipelined
// G prefetch) + staging; waves 1-2: helpers (2 M rows x 16 cols per lane).
__global__ __launch_bounds__(192, 1) void scan9(
    const float* __restrict__ kallT, const float* __restrict__ thr2_all,
    const float* __restrict__ inv_all, const float* __restrict__ Gg,
    float* __restrict__ readv)
{
  __shared__ float kS[3][CC * 68];   // raw k chunks [t][feature]
  __shared__ float GS[2][CC * CC];   // normalized Gram, double-buffered
  __shared__ float rS[CC * 64];      // err0 = k - (M k)*inv per feature
  __shared__ float cstS[CC * 64];    // gated raw err

  const int b = blockIdx.x, tid = threadIdx.x;
  const int w = tid >> 6, l = tid & 63;
  const int A = l >> 2, B4 = l & 3;
  const int r0 = 32 * (w - 1) + 2 * A;   // helper feature rows (w>0)
  const int jb = 16 * B4;
  const size_t gbase = (size_t)b * LSEQ;

  float M0[16], M1[16], acc[32];
  #pragma unroll
  for (int q = 0; q < 16; ++q) { M0[q] = 0.f; M1[q] = 0.f; }

// A2: rS[t] = k_t - (M . k_t)*inv_t for t in [T0,T0+16), helper waves
#define A2_SLICE(KB, IVP, T0) do {                                             \
    _Pragma("unroll")                                                          \
    for (int t = (T0); t < (T0) + 16; ++t) {                                   \
      const float* kr = &kS[KB][t * 68 + jb];                                  \
      float p0a=0.f,p0b=0.f,p1a=0.f,p1b=0.f;                                   \
      _Pragma("unroll")                                                        \
      for (int q2 = 0; q2 < 4; ++q2) {                                         \
        const float4 kv = ((const float4*)kr)[q2];                             \
        p0a = fmaf(M0[4*q2+0], kv.x, p0a); p0b = fmaf(M0[4*q2+1], kv.y, p0b);  \
        p0a = fmaf(M0[4*q2+2], kv.z, p0a); p0b = fmaf(M0[4*q2+3], kv.w, p0b);  \
        p1a = fmaf(M1[4*q2+0], kv.x, p1a); p1b = fmaf(M1[4*q2+1], kv.y, p1b);  \
        p1a = fmaf(M1[4*q2+2], kv.z, p1a); p1b = fmaf(M1[4*q2+3], kv.w, p1b);  \
      }                                                                        \
      float p0 = quad_sum(p0a + p0b);                                          \
      float p1 = quad_sum(p1a + p1b);                                          \
      const float iv = (IVP)[t];                     /* uniform -> s_load */   \
      const float2 kv2 = *(const float2*)&kS[KB][t * 68 + r0];                 \
      if (B4 == 0)                                                             \
        *(float2*)&rS[t * 64 + r0] = make_float2(kv2.x - p0 * iv,              \
                                                 kv2.y - p1 * iv);             \
    }                                                                          \
  } while (0)

// C: M += (cstS[s]*inv[s]) (x) k_s for s in [S0,S0+16), helper waves
#define C_SLICE(KB, IVP, S0) do {                                              \
    _Pragma("unroll")                                                          \
    for (int s = (S0); s < (S0) + 16; ++s) {                                   \
      const float2 cc2 = *(const float2*)&cstS[s * 64 + r0];                   \
      const float iv = (IVP)[s];                     /* uniform -> s_load */   \
      const float c0 = cc2.x * iv, c1 = cc2.y * iv;                            \
      const float* kr = &kS[KB][s * 68 + jb];                                  \
      _Pragma("unroll")                                                        \
      for (int q2 = 0; q2 < 4; ++q2) {                                         \
        const float4 kv = ((const float4*)kr)[q2];                             \
        M0[4*q2+0] = fmaf(c0, kv.x, M0[4*q2+0]); M0[4*q2+1] = fmaf(c0, kv.y, M0[4*q2+1]); \
        M0[4*q2+2] = fmaf(c0, kv.z, M0[4*q2+2]); M0[4*q2+3] = fmaf(c0, kv.w, M0[4*q2+3]); \
        M1[4*q2+0] = fmaf(c1, kv.x, M1[4*q2+0]); M1[4*q2+1] = fmaf(c1, kv.y, M1[4*q2+1]); \
        M1[4*q2+2] = fmaf(c1, kv.z, M1[4*q2+2]); M1[4*q2+3] = fmaf(c1, kv.w, M1[4*q2+3]); \
      }                                                                        \
    }                                                                          \
  } while (0)

// B: serial gate core, tokens [16Q,16Q+16). G row t+1 prefetched into regs
// while token t's wave_sum/gate runs (hides LDS latency on the serial path).
// Triangular update with compile-time quad bounds.
#define B_SLICE(Q, GSB, THP, LASTCH) do {                                      \
    const int t0_ = 16 * (Q);                                                  \
    float rsv[16];                                                             \
    _Pragma("unroll")                                                          \
    for (int i = 0; i < 16; ++i) rsv[i] = rS[(t0_ + i) * 64 + l];              \
    _Pragma("unroll")                                                          \
    for (int i = 0; i < 16; ++i) acc[t0_ + i] += rsv[i];                       \
    float g[32];                                                               \
    {                                                                          \
      const float4* gp = (const float4*)&GS[GSB][t0_ * CC];                    \
      _Pragma("unroll")                                                        \
      for (int r = (t0_ + 1) >> 2; r < 8; ++r) {                               \
        const float4 v = gp[r];                                                \
        g[4*r]=v.x; g[4*r+1]=v.y; g[4*r+2]=v.z; g[4*r+3]=v.w;                  \
      }                                                                        \
    }                                                                          \
    _Pragma("unroll")                                                          \
    for (int i = 0; i < 16; ++i) {                                             \
      const int t = t0_ + i;                                                   \
      const float err = acc[t];                                                \
      const float ne2 = wave_sum(err * err);                                   \
      float gn[32];                                                            \
      if (i < 15) {                                                            \
        const float4* gp = (const float4*)&GS[GSB][(t + 1) * CC];              \
        _Pragma("unroll")                                                      \
        for (int r = (t + 2) >> 2; r < 8; ++r) {                               \
          const float4 v = gp[r];                                              \
          gn[4*r]=v.x; gn[4*r+1]=v.y; gn[4*r+2]=v.z; gn[4*r+3]=v.w;            \
        }                                                                      \
      }                                                                        \
      bool gate = (ne2 >= (THP)[t]);                                           \
      if ((LASTCH) && t == CC - 1) gate = false;                               \
      const float c = gate ? err : 0.f;                                        \
      cstS[t * 64 + l] = c;                                                    \
      _Pragma("unroll")                                                        \
      for (int u = t + 1; u < CC; ++u) acc[u] = fmaf(-g[u], c, acc[u]);        \
      if (i < 15) {                                                            \
        _Pragma("unroll")                                                      \
        for (int r = (t + 2) >> 2; r < 8; ++r) {                               \
          g[4*r]=gn[4*r]; g[4*r+1]=gn[4*r+1]; g[4*r+2]=gn[4*r+2]; g[4*r+3]=gn[4*r+3]; \
        }                                                                      \
      }                                                                        \
    }                                                                          \
  } while (0)

  // ---- prologue: stage chunk 0 (waves 0,1) + G chunk 0 (wave 2) ----
  if (w < 2) {
    const float* src = kallT + (size_t)l * NT + gbase + w * 16;
    #pragma unroll
    for (int q = 0; q < 4; ++q) {
      const float4 v = ((const float4*)src)[q];
      const int t0 = w * 16 + q * 4;
      kS[0][(t0+0)*68 + l] = v.x; kS[0][(t0+1)*68 + l] = v.y;
      kS[0][(t0+2)*68 + l] = v.z; kS[0][(t0+3)*68 + l] = v.w;
    }
  } else {
    const float4* gsrc = (const float4*)(Gg + (size_t)b * NCH * (CC * CC));
    #pragma unroll
    for (int q = 0; q < 4; ++q) ((float4*)GS[0])[q * 64 + l] = gsrc[q * 64 + l];
  }
  __syncthreads();

  for (int ch = 0; ch < NCH; ++ch) {
    const int cb = ch % 3, pb = (ch + 2) % 3, nb = (ch + 1) % 3;
    const int cg = ch & 1, ng = 1 - cg;
    const bool lastch = (ch == NCH - 1);
    const float* ivcur = inv_all  + gbase + ch * CC;
    const float* ivprv = inv_all  + gbase + (ch - 1) * CC;
    const float* thcur = thr2_all + gbase + ch * CC;

    // ---- P0: wave0 zero acc + stage k(ch+1), G(ch+1); helpers C(ch-1) tail + A2 0..16
    if (w == 0) {
      #pragma unroll
      for (int u = 0; u < 32; ++u) acc[u] = 0.f;
      if (!lastch) {
        const float* src = kallT + (size_t)l * NT + gbase + (ch + 1) * CC;
        #pragma unroll
        for (int q = 0; q < 8; ++q) {
          const float4 v = ((const float4*)src)[q];
          const int t0 = q * 4;
          kS[nb][(t0+0)*68 + l] = v.x; kS[nb][(t0+1)*68 + l] = v.y;
          kS[nb][(t0+2)*68 + l] = v.z; kS[nb][(t0+3)*68 + l] = v.w;
        }
        const float4* gsrc = (const float4*)(Gg + ((size_t)b * NCH + ch + 1) * (CC * CC));
        #pragma unroll
        for (int q = 0; q < 4; ++q) ((float4*)GS[ng])[q * 64 + l] = gsrc[q * 64 + l];
      }
    } else {
      if (ch > 0) C_SLICE(pb, ivprv, 16);
      A2_SLICE(cb, ivcur, 0);
    }
    __syncthreads();

    // ---- P1: B tokens 0..16 ; helpers A2 16..32 ----
    if (w == 0) B_SLICE(0, cg, thcur, lastch);
    else        A2_SLICE(cb, ivcur, 16);
    __syncthreads();

    // ---- P2: B tokens 16..32 ; helpers C(ch) 0..16 ----
    if (w == 0) B_SLICE(1, cg, thcur, lastch);
    else        C_SLICE(cb, ivcur, 0);
    __syncthreads();
  }

  // ---- epilogue: helpers C(31) tail + final read = M . k[1023] ----
  if (w > 0) {
    constexpr int fb = (NCH - 1) % 3;   // = 1
    const float* iv31 = inv_all + gbase + (NCH - 1) * CC;
    C_SLICE(fb, iv31, 16);
    const float* kr = &kS[fb][(CC - 1) * 68 + jb];
    float p0a=0.f,p0b=0.f,p1a=0.f,p1b=0.f;
    #pragma unroll
    for (int q2 = 0; q2 < 4; ++q2) {
      const float4 kv = ((const float4*)kr)[q2];
      p0a = fmaf(M0[4*q2+0], kv.x, p0a); p0b = fmaf(M0[4*q2+1], kv.y, p0b);
      p0a = fmaf(M0[4*q2+2], kv.z, p0a); p0b = fmaf(M0[4*q2+3], kv.w, p0b);
      p1a = fmaf(M1[4*q2+0], kv.x, p1a); p1b = fmaf(M1[4*q2+1], kv.y, p1b);
      p1a = fmaf(M1[4*q2+2], kv.z, p1a); p1b = fmaf(M1[4*q2+3], kv.w, p1b);
    }
    float d0 = quad_sum(p0a + p0b);
    float d1 = quad_sum(p1a + p1b);
    if (B4 == 0) *(float2*)&readv[b * 64 + r0] = make_float2(d0, d1);
  }
#undef A2_SLICE
#undef C_SLICE
#undef B_SLICE
}

// ---------- Kernel 4: r2T[i][b] = (read @ rpW + rpb)^T ----------
__global__ __launch_bounds__(64) void rproj_kernel(const float* __restrict__ readv,
    const float* __restrict__ rpW, const float* __restrict__ rpb, float* __restrict__ r2T)
{
  const int b = blockIdx.x, i = threadIdx.x;
  const float* rv = readv + b * 64;
  float acc = rpb[i];
  #pragma unroll
  for (int j = 0; j < 64; ++j)
    acc = fmaf(rv[j], rpW[j * 64 + i], acc);
  r2T[i * 64 + b] = acc;
}

// ---------- Kernel 5: out = r2 @ outW + outb ----------
__global__ __launch_bounds__(256, 1) void out_kernel(const float* __restrict__ r2T,
    const float* __restrict__ outW, const float* __restrict__ outb,
    float* __restrict__ out)
{
  const int v = blockIdx.x * 256 + threadIdx.x;
  float acc[64];
  #pragma unroll
  for (int b = 0; b < 64; ++b) acc[b] = 0.f;
  for (int k = 0; k < 64; ++k) {
    const float wv = outW[(size_t)k * NV + v];
    const float* rr = r2T + k * 64;           // uniform row -> s_load
    #pragma unroll
    for (int b = 0; b < 64; ++b)
      acc[b] = fmaf(rr[b], wv, acc[b]);
  }
  const float ob = outb[v];
  #pragma unroll
  for (int b = 0; b < 64; ++b)
    out[(size_t)b * NV + v] = acc[b] + ob;
}

extern "C" void kernel_launch(void* const* d_in, const int* in_sizes, int n_in,
                              void* d_out, int out_size, void* d_ws, size_t ws_size,
                              hipStream_t stream)
{
  const int*   seq   = (const int*)d_in[0];
  const float* embed = (const float*)d_in[1];
  const float* W1    = (const float*)d_in[2];
  const float* b1    = (const float*)d_in[3];
  const float* W2    = (const float*)d_in[4];
  const float* b2    = (const float*)d_in[5];
  const float* gam   = (const float*)d_in[6];
  const float* bet   = (const float*)d_in[7];
  const float* kpW   = (const float*)d_in[8];
  const float* rpW   = (const float*)d_in[9];
  const float* rpb   = (const float*)d_in[10];
  const float* outW  = (const float*)d_in[11];
  const float* outb  = (const float*)d_in[12];
  float* out = (float*)d_out;

  float* ws = (float*)d_ws;
  float* kallT = ws;                                    // 4,194,304 f  [feat][tok]
  float* G     = kallT + (size_t)HDIM * NT;             // 2,097,152 f
  float* thr2  = G     + (size_t)NB * NCH * CC * CC;    //    65,536 f
  float* inv   = thr2  + NT;                            //    65,536 f
  float* readv = inv   + NT;                            //     4,096 f
  float* r2T   = readv + NB * HDIM;                     //     4,096 f
  float* W1T   = r2T   + NB * HDIM;                     //     8,192 f
  float* kpWT  = W1T   + 8192;                          //     4,096 f

  hipLaunchKernelGGL(transpose_w, dim3(48), dim3(256), 0, stream, W1, kpW, W1T, kpWT);
  hipLaunchKernelGGL(tok4, dim3(256), dim3(256), 0, stream,
                     seq, embed, W1T, b1, W2, b2, gam, bet, kpWT, kallT, thr2, inv);
  hipLaunchKernelGGL(gram3, dim3(NB * 8), dim3(256), 0, stream, kallT, inv, G);
  hipLaunchKernelGGL(scan9, dim3(NB), dim3(192), 0, stream, kallT, thr2, inv, G, readv);
  hipLaunchKernelGGL(rproj_kernel, dim3(NB), dim3(64), 0, stream, readv, rpW, rpb, r2T);
  hipLaunchKernelGGL(out_kernel, dim3(NV / 256), dim3(256), 0, stream, r2T, outW, outb, out);
}